// Round 11
// baseline (106.193 us; speedup 1.0000x reference)
//
#include <hip/hip_runtime.h>

// DispCorrLayer: out[b,d,h,w] = (1/C) * sum_c in1[b,c,h,w] * in2[b,c,h,w-(D-d)]
// (zero when w + d < D). B=4 C=32 H=256 W=512 D=128, fp32.
//
// R11 = R8 compute/epilogue (banded-GEMM MFMA + LDS diagonal transpose,
// OBS=20, folded 1/32 scale, nt stores) made PERSISTENT:
//  - 512 blocks (2/CU), each runs 4 work items (b, h, w-half): same b,
//    two adjacent h x both w-halves (in2 halo L2 reuse).
//  - cross-item software pipeline: issue item k+1's ~96 global loads into
//    registers BEFORE computing item k (sched_barrier(0) pins the order);
//    pack+LDS-commit after the compute's barrier. HBM latency of staging
//    hides under ~10K cycles of MFMA/scatter/store.

#define BB 4
#define CC 32
#define HH 256
#define WW 512
#define DD 128
#define HW (HH * WW)

#define NT 256               // 4 waves
#define WHALF 256            // w span per item
#define S2N 384              // staged in2 cols: w' in [wb-128, wb+256)
#define OBS 20               // ob row stride (words): 16B-aligned rows
#define NITEMS 4
#define NBLK 512

typedef __attribute__((ext_vector_type(8))) short bf16x8;
typedef __attribute__((ext_vector_type(4))) float f32x4;

__device__ __forceinline__ unsigned int pack2(float a, float b) {
    // RNE bf16 round: a -> low half, b -> high half
    union { float f; unsigned int i; } x, y; x.f = a; y.f = b;
    unsigned int xi = x.i + 0x7fffu + ((x.i >> 16) & 1u);
    unsigned int yi = y.i + 0x7fffu + ((y.i >> 16) & 1u);
    return (xi >> 16) | (yi & 0xffff0000u);
}

// word index of the 16B chunk holding row `row`, k-chunk `kc` (8 bf16).
__device__ __forceinline__ int cidx(int row, int kc) {
    return (row * 4 + (kc ^ ((row >> 1) & 3))) * 4;
}

__global__ __launch_bounds__(NT, 2)
void disp_corr_kernel(const float* __restrict__ in1,
                      const float* __restrict__ in2,
                      float* __restrict__ out) {
    __shared__ __align__(16) unsigned int s1t[WHALF * 16];  // in1^T bf16, 16 KB
    __shared__ __align__(16) unsigned int s2t[S2N * 16];    // in2^T bf16, 24 KB
    __shared__ __align__(16) float ob[4][DD * OBS];         // band buf, 40 KB

    const int t = threadIdx.x;

    // XCD swizzle (bijective, 512 = 8*64) on persistent-block id
    const int gid = (blockIdx.x & 7) * (NBLK / 8) + (blockIdx.x >> 3);
    const int item0 = gid * NITEMS;

    const float sc = 1.0f / (float)CC;
    const bool rep1 = (t < S2N - NT);                // t < 128

    float v1[CC], v2[CC], v3[CC];

    // ---- issue item w's ~96 staging loads into registers ----
    auto load_item = [&](int wk) {
        const int wh = wk & 1;
        const int h  = (wk >> 1) & (HH - 1);
        const int b  = wk >> 9;
        const int wb = wh * WHALF;
        const float* p1 = in1 + (size_t)b * CC * HW + (size_t)h * WW + wb;
        const float* p2 = in2 + (size_t)b * CC * HW + (size_t)h * WW;
        #pragma unroll
        for (int c = 0; c < CC; ++c) v1[c] = p1[(size_t)c * HW + t];
        const int wp0 = wb + t - DD;
        if (wp0 >= 0) {
            #pragma unroll
            for (int c = 0; c < CC; ++c) v2[c] = p2[(size_t)c * HW + wp0];
        } else {
            #pragma unroll
            for (int c = 0; c < CC; ++c) v2[c] = 0.f;
        }
        const int wp1 = wb + DD + t;                 // in [128, 512)
        if (rep1) {
            #pragma unroll
            for (int c = 0; c < CC; ++c) v3[c] = p2[(size_t)c * HW + wp1];
        }
    };

    // ---- pack staged registers -> LDS ----
    auto pack_item = [&]() {
        #pragma unroll
        for (int kc = 0; kc < 4; ++kc) {
            unsigned int u[4];
            #pragma unroll
            for (int ci = 0; ci < 4; ++ci)
                u[ci] = pack2(v1[kc * 8 + 2 * ci] * sc,
                              v1[kc * 8 + 2 * ci + 1] * sc);
            *(uint4*)&s1t[cidx(t, kc)] = make_uint4(u[0], u[1], u[2], u[3]);
        }
        #pragma unroll
        for (int kc = 0; kc < 4; ++kc) {
            unsigned int u[4];
            #pragma unroll
            for (int ci = 0; ci < 4; ++ci)
                u[ci] = pack2(v2[kc * 8 + 2 * ci], v2[kc * 8 + 2 * ci + 1]);
            *(uint4*)&s2t[cidx(t, kc)] = make_uint4(u[0], u[1], u[2], u[3]);
        }
        if (rep1) {
            #pragma unroll
            for (int kc = 0; kc < 4; ++kc) {
                unsigned int u[4];
                #pragma unroll
                for (int ci = 0; ci < 4; ++ci)
                    u[ci] = pack2(v3[kc * 8 + 2 * ci], v3[kc * 8 + 2 * ci + 1]);
                *(uint4*)&s2t[cidx(NT + t, kc)] = make_uint4(u[0], u[1], u[2], u[3]);
            }
        }
    };

    // per-lane compute constants
    const int lane = t & 63;
    const int wv   = t >> 6;
    const int cl   = lane & 15;       // fragment col (w' within tile)
    const int rg   = lane >> 4;       // fragment row group (w)
    float* myob = ob[wv];
    const int dq = lane >> 2;         // store phase: d within 16-group
    const int j  = lane & 3;          // store phase: w-quad

    // ---- compute + store one item from LDS ----
    auto compute_item = [&](int wk) {
        const int wh = wk & 1;
        const int h  = (wk >> 1) & (HH - 1);
        const int b  = wk >> 9;
        const int wb = wh * WHALF;
        const size_t obase = (size_t)b * DD * HW + (size_t)h * WW + wb;
        #pragma unroll
        for (int ii = 0; ii < 4; ++ii) {
            const int i = wv * 4 + ii;             // local w-tile 0..15
            union { uint4 u; bf16x8 v; } a;
            a.u = *(const uint4*)&s1t[cidx(i * 16 + cl, rg)];
            #pragma unroll
            for (int mm = 0; mm <= 8; ++mm) {
                union { uint4 u; bf16x8 v; } bq;
                bq.u = *(const uint4*)&s2t[cidx((i + mm) * 16 + cl, rg)];
                f32x4 acc = {0.f, 0.f, 0.f, 0.f};
                acc = __builtin_amdgcn_mfma_f32_16x16x32_bf16(a.v, bq.v, acc,
                                                              0, 0, 0);
                #pragma unroll
                for (int q = 0; q < 4; ++q) {
                    const int r = rg * 4 + q;
                    const int d = mm * 16 + cl - r;
                    const bool ok = (mm == 0) ? (cl >= r)
                                  : (mm == 8) ? (cl < r) : true;
                    if (ok) myob[d * OBS + r] = acc[q];
                }
            }
            #pragma unroll
            for (int dg = 0; dg < 8; ++dg) {
                const int d = dg * 16 + dq;
                f32x4 v = *(const f32x4*)&myob[d * OBS + 4 * j];
                __builtin_nontemporal_store(
                    v, (f32x4*)(out + obase + (size_t)d * HW + i * 16 + 4 * j));
            }
        }
    };

    // ---- pipeline: load(k+1) under compute(k) ----
    load_item(item0);
    pack_item();
    __syncthreads();
    for (int k = 0; k < NITEMS; ++k) {
        if (k + 1 < NITEMS) load_item(item0 + k + 1);
        __builtin_amdgcn_sched_barrier(0);   // keep loads issued before compute
        compute_item(item0 + k);
        __syncthreads();                     // all waves done reading LDS
        if (k + 1 < NITEMS) {
            pack_item();
            __syncthreads();
        }
    }
}

extern "C" void kernel_launch(void* const* d_in, const int* in_sizes, int n_in,
                              void* d_out, int out_size, void* d_ws, size_t ws_size,
                              hipStream_t stream) {
    const float* in1 = (const float*)d_in[0];
    const float* in2 = (const float*)d_in[1];
    float* out = (float*)d_out;
    disp_corr_kernel<<<NBLK, NT, 0, stream>>>(in1, in2, out);
}

// Round 12
// 86.852 us; speedup vs baseline: 1.2227x; 1.2227x over previous
//
#include <hip/hip_runtime.h>

// DispCorrLayer: out[b,d,h,w] = (1/C) * sum_c in1[b,c,h,w] * in2[b,c,h,w-(D-d)]
// (zero when w + d < D). B=4 C=32 H=256 W=512 D=128, fp32.
//
// R12 = R8's banded-GEMM MFMA + LDS diagonal-transpose, restructured for
// 2x occupancy: 8 waves/block, each wave owns 2 w-tiles, and the per-wave
// band buffer is halved to [64][20] by splitting each tile's 9 MFMAs into
// d<64 (mm=0..4) and d>=64 (mm=4..8) phases (mm=4's acc straddles; kept in
// registers and scattered into both halves). LDS = 16+24+40 = 80 KB ->
// 2 blocks/CU = 16 waves/CU = 4 waves/SIMD (R8 had 2). Single barrier;
// after it waves drift freely so MFMA/scatter of one wave hides another's
// readback + nt-store latency.

#define BB 4
#define CC 32
#define HH 256
#define WW 512
#define DD 128
#define HW (HH * WW)

#define NT 512               // 8 waves
#define WHALF 256            // w span per block
#define S2N 384              // staged in2 cols: w' in [wb-128, wb+256)
#define OBS 20               // ob row stride (words): 16B-aligned rows

typedef __attribute__((ext_vector_type(8))) short bf16x8;
typedef __attribute__((ext_vector_type(4))) float f32x4;

__device__ __forceinline__ unsigned int pack2(float a, float b) {
    // RNE bf16 round: a -> low half, b -> high half
    union { float f; unsigned int i; } x, y; x.f = a; y.f = b;
    unsigned int xi = x.i + 0x7fffu + ((x.i >> 16) & 1u);
    unsigned int yi = y.i + 0x7fffu + ((y.i >> 16) & 1u);
    return (xi >> 16) | (yi & 0xffff0000u);
}

// word index of the 16B chunk holding row `row`, k-chunk `kc` (8 bf16).
__device__ __forceinline__ int cidx(int row, int kc) {
    return (row * 4 + (kc ^ ((row >> 1) & 3))) * 4;
}

__global__ __launch_bounds__(NT, 2)
void disp_corr_kernel(const float* __restrict__ in1,
                      const float* __restrict__ in2,
                      float* __restrict__ out) {
    __shared__ __align__(16) unsigned int s1t[WHALF * 16];  // in1^T bf16, 16 KB
    __shared__ __align__(16) unsigned int s2t[S2N * 16];    // in2^T bf16, 24 KB
    __shared__ __align__(16) float ob[8][64 * OBS];         // half-band, 40 KB

    const int t = threadIdx.x;

    // XCD swizzle (bijective, 2048 = 8*256)
    const int xcd = blockIdx.x & 7, slot = blockIdx.x >> 3;
    const int work = (xcd << 8) + slot;
    const int wh = work & 1;
    const int h  = (work >> 1) & (HH - 1);
    const int b  = work >> 9;
    const int wb = wh * WHALF;

    const float* p1 = in1 + (size_t)b * CC * HW + (size_t)h * WW + wb;
    const float* p2 = in2 + (size_t)b * CC * HW + (size_t)h * WW;
    const float sc = 1.0f / (float)CC;

    // ---- staging: 2560 uint4-units (s1:1024, s2:1536), 5 per thread ----
    // unit u: row = v>>2, kc = v&3; 8 scalar loads -> 1 packed uint4.
    float vv[5][8];
    #pragma unroll
    for (int k = 0; k < 5; ++k) {
        const int u = t + k * NT;
        const bool one = (u < 1024);
        const int v = one ? u : u - 1024;
        const int row = v >> 2, kc = v & 3;
        if (one) {
            #pragma unroll
            for (int ci = 0; ci < 8; ++ci)
                vv[k][ci] = p1[(size_t)(kc * 8 + ci) * HW + row];
        } else {
            const int wp = wb + row - DD;
            if (wp >= 0) {
                #pragma unroll
                for (int ci = 0; ci < 8; ++ci)
                    vv[k][ci] = p2[(size_t)(kc * 8 + ci) * HW + wp];
            } else {
                #pragma unroll
                for (int ci = 0; ci < 8; ++ci) vv[k][ci] = 0.f;
            }
        }
    }
    #pragma unroll
    for (int k = 0; k < 5; ++k) {
        const int u = t + k * NT;
        const bool one = (u < 1024);
        const int v = one ? u : u - 1024;
        const int row = v >> 2, kc = v & 3;
        const float m = one ? sc : 1.0f;
        unsigned int uw[4];
        #pragma unroll
        for (int ci = 0; ci < 4; ++ci)
            uw[ci] = pack2(vv[k][2 * ci] * m, vv[k][2 * ci + 1] * m);
        unsigned int* dst = one ? &s1t[cidx(row, kc)] : &s2t[cidx(row, kc)];
        *(uint4*)dst = make_uint4(uw[0], uw[1], uw[2], uw[3]);
    }
    __syncthreads();

    // ---- per wave: 2 w-tiles; per tile 9 MFMAs in two d-half phases ----
    const int lane = t & 63;
    const int wv   = t >> 6;
    const int cl   = lane & 15;       // fragment col (w' within tile)
    const int rg   = lane >> 4;       // fragment row group (w)
    float* myob = ob[wv];
    const size_t obase = (size_t)b * DD * HW + (size_t)h * WW + wb;

    const int dq = lane >> 2;         // store phase: d within 16-group
    const int j  = lane & 3;          // store phase: w-quad

    #pragma unroll
    for (int ii = 0; ii < 2; ++ii) {
        const int i = wv * 2 + ii;                 // local w-tile 0..15
        union { uint4 u; bf16x8 v; } a;
        a.u = *(const uint4*)&s1t[cidx(i * 16 + cl, rg)];

        f32x4 acc4;                                // mm=4 straddle result
        // ---- phase A: mm = 0..4, d < 64 ----
        #pragma unroll
        for (int mm = 0; mm <= 4; ++mm) {
            union { uint4 u; bf16x8 v; } bq;
            bq.u = *(const uint4*)&s2t[cidx((i + mm) * 16 + cl, rg)];
            f32x4 acc = {0.f, 0.f, 0.f, 0.f};
            acc = __builtin_amdgcn_mfma_f32_16x16x32_bf16(a.v, bq.v, acc, 0, 0, 0);
            #pragma unroll
            for (int q = 0; q < 4; ++q) {
                const int r = rg * 4 + q;
                const int d = mm * 16 + cl - r;    // true d
                const bool ok = (mm == 0) ? (cl >= r)
                              : (mm == 4) ? (cl < r) : true;
                if (ok) myob[d % 64 * OBS + r] = acc[q];
            }
            if (mm == 4) acc4 = acc;
        }
        // readback + store d in [0,64)
        #pragma unroll
        for (int dg = 0; dg < 4; ++dg) {
            const int d = dg * 16 + dq;
            f32x4 v = *(const f32x4*)&myob[d * OBS + 4 * j];
            __builtin_nontemporal_store(
                v, (f32x4*)(out + obase + (size_t)d * HW + i * 16 + 4 * j));
        }
        // ---- phase B: mm = 4..8, d >= 64 (local row = d - 64) ----
        #pragma unroll
        for (int q = 0; q < 4; ++q) {              // mm=4, cl >= r half
            const int r = rg * 4 + q;
            if (cl >= r) myob[(cl - r) * OBS + r] = acc4[q];
        }
        #pragma unroll
        for (int mm = 5; mm <= 8; ++mm) {
            union { uint4 u; bf16x8 v; } bq;
            bq.u = *(const uint4*)&s2t[cidx((i + mm) * 16 + cl, rg)];
            f32x4 acc = {0.f, 0.f, 0.f, 0.f};
            acc = __builtin_amdgcn_mfma_f32_16x16x32_bf16(a.v, bq.v, acc, 0, 0, 0);
            #pragma unroll
            for (int q = 0; q < 4; ++q) {
                const int r = rg * 4 + q;
                const int dl = (mm - 4) * 16 + cl - r;   // d - 64
                const bool ok = (mm == 8) ? (cl < r) : true;
                if (ok) myob[dl * OBS + r] = acc[q];
            }
        }
        // readback + store d in [64,128)
        #pragma unroll
        for (int dg = 4; dg < 8; ++dg) {
            const int d = dg * 16 + dq;
            f32x4 v = *(const f32x4*)&myob[(d - 64) * OBS + 4 * j];
            __builtin_nontemporal_store(
                v, (f32x4*)(out + obase + (size_t)d * HW + i * 16 + 4 * j));
        }
    }
}

extern "C" void kernel_launch(void* const* d_in, const int* in_sizes, int n_in,
                              void* d_out, int out_size, void* d_ws, size_t ws_size,
                              hipStream_t stream) {
    const float* in1 = (const float*)d_in[0];
    const float* in2 = (const float*)d_in[1];
    float* out = (float*)d_out;
    const int nblocks = BB * HH * 2;             // 2048
    disp_corr_kernel<<<nblocks, NT, 0, stream>>>(in1, in2, out);
}